// Round 4
// baseline (766.998 us; speedup 1.0000x reference)
//
#include <hip/hip_runtime.h>
#include <hip/hip_bf16.h>
#include <math.h>

#define H 256
#define EDIM 6
#define NEG 0.2f
#define LN_EPS 1e-5f
#define NPAD 20096   // 157 * 128

typedef __bf16 bf16x8 __attribute__((ext_vector_type(8)));
typedef float  floatx4 __attribute__((ext_vector_type(4)));

__device__ __forceinline__ float b2f(unsigned short u) {
    union { unsigned int i; float f; } v; v.i = ((unsigned int)u) << 16; return v.f;
}
__device__ __forceinline__ unsigned short f2bu(float f) {
    __hip_bfloat16 h = __float2bfloat16(f);
    return *(unsigned short*)&h;
}

// ---------------------------------------------------------------------------
// CSR build
// ---------------------------------------------------------------------------
__global__ void k_edge_hist(const int* __restrict__ ei, int* __restrict__ deg, int E) {
    int e = blockIdx.x * blockDim.x + threadIdx.x;
    if (e >= E) return;
    atomicAdd(&deg[ei[E + e]], 1);
}

__global__ void k_scan(const int* __restrict__ deg, int* __restrict__ row_ptr,
                       int* __restrict__ cursor, int N, int E) {
    __shared__ int wsum[16];
    __shared__ int wpre[16];
    __shared__ int s_carry;
    int tid = threadIdx.x;
    int lane = tid & 63, wv = tid >> 6;
    if (tid == 0) s_carry = 0;
    __syncthreads();
    for (int base = 0; base < N; base += 1024) {
        int i = base + tid;
        int v = (i < N) ? deg[i] : 0;
        int x = v;
#pragma unroll
        for (int d = 1; d < 64; d <<= 1) {
            int y = __shfl_up(x, d);
            if (lane >= d) x += y;
        }
        if (lane == 63) wsum[wv] = x;
        __syncthreads();
        int total = 0;
        if (tid == 0) {
            int a = 0;
            for (int w = 0; w < 16; w++) { wpre[w] = a; a += wsum[w]; }
            total = a;
        }
        __syncthreads();
        int excl = s_carry + wpre[wv] + (x - v);
        if (i < N) { row_ptr[i] = excl; cursor[i] = excl; }
        __syncthreads();
        if (tid == 0) s_carry += total;
        __syncthreads();
    }
    if (tid == 0) row_ptr[N] = E;
}

// Packed edge record: {src:int, 6 x bf16 attrs} = 16 B
__global__ void k_scatter(const int* __restrict__ ei, const float* __restrict__ eattr,
                          int* __restrict__ cursor, int4* __restrict__ erec, int E) {
    int e = blockIdx.x * blockDim.x + threadIdx.x;
    if (e >= E) return;
    int s = ei[e], d = ei[E + e];
    int pos = atomicAdd(&cursor[d], 1);
    int4 r;
    r.x = s;
    r.y = (int)f2bu(eattr[e * EDIM + 0]) | ((int)f2bu(eattr[e * EDIM + 1]) << 16);
    r.z = (int)f2bu(eattr[e * EDIM + 2]) | ((int)f2bu(eattr[e * EDIM + 3]) << 16);
    r.w = (int)f2bu(eattr[e * EDIM + 4]) | ((int)f2bu(eattr[e * EDIM + 5]) << 16);
    erec[pos] = r;
}

// ---------------------------------------------------------------------------
// Weight conversions to transposed bf16 [c][k]
// ---------------------------------------------------------------------------
__global__ void k_conv_x(const float* __restrict__ x, __hip_bfloat16* __restrict__ xb, int N) {
    int idx = blockIdx.x * blockDim.x + threadIdx.x;
    if (idx >= NPAD * 32) return;
    int r = idx >> 5, k = idx & 31;
    float v = (r < N && k < 23) ? x[r * 23 + k] : 0.f;
    xb[idx] = __float2bfloat16(v);
}

__global__ void k_conv_w0(const float* __restrict__ Wl0, const float* __restrict__ Wr0,
                          __hip_bfloat16* __restrict__ out) {
    int idx = blockIdx.x * blockDim.x + threadIdx.x;
    if (idx >= 2 * 256 * 32) return;
    int mat = idx >> 13, rem = idx & 8191;
    int c = rem >> 5, k = rem & 31;
    const float* W = mat ? Wr0 : Wl0;
    float v = (k < 23) ? W[k * 256 + c] : 0.f;
    out[idx] = __float2bfloat16(v);
}

__global__ void k_conv_w(const float* __restrict__ Wl, const float* __restrict__ Wr,
                         const float* __restrict__ lin, __hip_bfloat16* __restrict__ out) {
    int idx = blockIdx.x * blockDim.x + threadIdx.x;
    if (idx >= 7 * 65536) return;
    int mat = idx >> 16, rem = idx & 65535;
    int c = rem >> 8, k = rem & 255;
    const float* W = (mat < 3) ? (Wl + (size_t)mat * 65536)
                   : (mat < 6) ? (Wr + (size_t)(mat - 3) * 65536)
                   : lin;
    out[idx] = __float2bfloat16(W[k * 256 + c]);
}

// ---------------------------------------------------------------------------
// MFMA dual GEMM, K as compile-time constant. mat0 emits bf16; mat1 emits f32.
// ---------------------------------------------------------------------------
template<int K>
__global__ __launch_bounds__(256) void k_gemm_mfma(
    const __hip_bfloat16* __restrict__ A, int N,
    const __hip_bfloat16* __restrict__ Wt1, const float* __restrict__ b1,
    float* __restrict__ C1f, unsigned short* __restrict__ C1b,
    const __hip_bfloat16* __restrict__ Wt2, const float* __restrict__ b2,
    float* __restrict__ C2) {
    int tid = threadIdx.x;
    int wv = tid >> 6, lane = tid & 63;
    int quad = lane >> 4, l16 = lane & 15;
    int mat = blockIdx.x >> 1;
    int c0 = (blockIdx.x & 1) * 128;
    int r0 = blockIdx.y * 128;
    const __hip_bfloat16* Wt = mat ? Wt2 : Wt1;
    const float* bv = mat ? b2 : b1;
    int wm = wv >> 1, wn = wv & 1;
    int rbase = r0 + wm * 64;
    int cbase = c0 + wn * 64;

    floatx4 acc[4][4] = {};
    const __bf16* Ab = (const __bf16*)A;
    const __bf16* Bb = (const __bf16*)Wt;
#pragma unroll 2
    for (int k0 = 0; k0 < K; k0 += 32) {
        bf16x8 a[4], b[4];
        const __bf16* Ap = Ab + (size_t)(rbase + l16) * K + k0 + quad * 8;
#pragma unroll
        for (int mi = 0; mi < 4; mi++)
            a[mi] = *(const bf16x8*)(Ap + (size_t)mi * 16 * K);
        const __bf16* Bp = Bb + (size_t)(cbase + l16) * K + k0 + quad * 8;
#pragma unroll
        for (int ni = 0; ni < 4; ni++)
            b[ni] = *(const bf16x8*)(Bp + (size_t)ni * 16 * K);
#pragma unroll
        for (int mi = 0; mi < 4; mi++)
#pragma unroll
            for (int ni = 0; ni < 4; ni++)
                acc[mi][ni] = __builtin_amdgcn_mfma_f32_16x16x32_bf16(a[mi], b[ni], acc[mi][ni], 0, 0, 0);
    }
#pragma unroll
    for (int ni = 0; ni < 4; ni++) {
        int c = cbase + ni * 16 + l16;
        float bb = bv[c];
#pragma unroll
        for (int mi = 0; mi < 4; mi++) {
#pragma unroll
            for (int r = 0; r < 4; r++) {
                int gr = rbase + mi * 16 + quad * 4 + r;
                if (gr >= N) continue;
                float val = acc[mi][ni][r] + bb;
                if (mat == 0) {
                    if (C1b) C1b[(size_t)gr * H + c] = f2bu(val);
                    if (C1f) C1f[(size_t)gr * H + c] = val;
                } else {
                    C2[(size_t)gr * H + c] = val;
                }
            }
        }
    }
}

// ---------------------------------------------------------------------------
// Fused GATv2 edge pass v3: one wave per node, packed 16B edge records,
// FLAT softmax (no running max -- logits bounded, shift-invariant), 4-edge
// groups, depth-2 software pipeline (records 2 ahead, gathers 1 ahead),
// fused bias+LayerNorm+ReLU, bf16 output.
// ---------------------------------------------------------------------------
#define LOADREC(R, g) do {                                                    \
    int _b = e0 + (g) * 4;                                                    \
    _Pragma("unroll")                                                         \
    for (int _i = 0; _i < 4; _i++) {                                          \
        int _ok = (_b + _i < e1);                                             \
        int _idx = _ok ? (_b + _i) : (e1 - 1);                                \
        int4 _t = erec[_idx];                                                 \
        if (!_ok) { _t.y = 0; _t.z = 0; _t.w = 0; }                           \
        R[_i] = _t;                                                           \
    }                                                                         \
} while (0)

#define GATHER(U, R) do {                                                     \
    _Pragma("unroll")                                                         \
    for (int _i = 0; _i < 4; _i++)                                            \
        U[_i] = *(const ushort4*)&hlb[(size_t)R[_i].x * H + cb];              \
} while (0)

__global__ __launch_bounds__(256) void k_gat(
    const unsigned short* __restrict__ hlb, const float* __restrict__ hr,
    const int* __restrict__ row_ptr, const int4* __restrict__ erec,
    const float* __restrict__ We, const float* __restrict__ attv,
    const float* __restrict__ bias, const float* __restrict__ lnw,
    const float* __restrict__ lnb, unsigned short* __restrict__ hout, int N) {
    int wv = threadIdx.x >> 6;
    int lane = threadIdx.x & 63;
    int node = blockIdx.x * 4 + wv;
    if (node >= N) return;
    int cb = lane * 4;

    float we[EDIM][4];
#pragma unroll
    for (int k = 0; k < EDIM; k++) {
        float4 t = *(const float4*)&We[k * H + cb];
        we[k][0] = t.x; we[k][1] = t.y; we[k][2] = t.z; we[k][3] = t.w;
    }
    float4 t;
    t = *(const float4*)&attv[cb];
    float av[4] = {t.x, t.y, t.z, t.w};
    t = *(const float4*)&hr[(size_t)node * H + cb];
    float hrd[4] = {t.x, t.y, t.z, t.w};
    ushort4 hu = *(const ushort4*)&hlb[(size_t)node * H + cb];
    float hli[4] = {b2f(hu.x), b2f(hu.y), b2f(hu.z), b2f(hu.w)};

    float denom = 0.f;
    float acc[4] = {0.f, 0.f, 0.f, 0.f};
    float es[EDIM] = {0.f, 0.f, 0.f, 0.f, 0.f, 0.f};

    int e0 = row_ptr[node], e1 = row_ptr[node + 1];
    int deg = e1 - e0;
    int groups = (deg + 3) >> 2;

    int4 recA[4], recB[4], recC[4];
    ushort4 gA[4], gB[4];

    if (groups > 0) {
        LOADREC(recA, 0);
        GATHER(gA, recA);
        if (groups > 1) LOADREC(recB, 1);
    }

    for (int g = 0; g < groups; g++) {
        if (g + 1 < groups) GATHER(gB, recB);
        if (g + 2 < groups) LOADREC(recC, g + 2);

        float hs[4][4], p4[4];
#pragma unroll
        for (int i = 0; i < 4; i++) {
            float ea[EDIM];
            ea[0] = b2f((unsigned short)(recA[i].y & 0xffff));
            ea[1] = b2f((unsigned short)(((unsigned)recA[i].y) >> 16));
            ea[2] = b2f((unsigned short)(recA[i].z & 0xffff));
            ea[3] = b2f((unsigned short)(((unsigned)recA[i].z) >> 16));
            ea[4] = b2f((unsigned short)(recA[i].w & 0xffff));
            ea[5] = b2f((unsigned short)(((unsigned)recA[i].w) >> 16));
#pragma unroll
            for (int k = 0; k < EDIM; k++) es[k] += ea[k];
            hs[i][0] = b2f(gA[i].x); hs[i][1] = b2f(gA[i].y);
            hs[i][2] = b2f(gA[i].z); hs[i][3] = b2f(gA[i].w);
            float pp = 0.f;
#pragma unroll
            for (int j = 0; j < 4; j++) {
                float v = hs[i][j] + hrd[j];
#pragma unroll
                for (int k = 0; k < EDIM; k++) v = fmaf(ea[k], we[k][j], v);
                v = (v > 0.f) ? v : NEG * v;
                pp = fmaf(v, av[j], pp);
            }
            p4[i] = pp;
        }
        // 4 independent butterflies, pipelined per stage
#pragma unroll
        for (int d = 1; d < 64; d <<= 1) {
#pragma unroll
            for (int i = 0; i < 4; i++) p4[i] += __shfl_xor(p4[i], d);
        }
        int base = g * 4;
        float w[4];
#pragma unroll
        for (int i = 0; i < 4; i++)
            w[i] = (base + i < deg) ? __expf(p4[i]) : 0.f;
        denom += (w[0] + w[1]) + (w[2] + w[3]);
#pragma unroll
        for (int j = 0; j < 4; j++) {
            float t0 = fmaf(w[0], hs[0][j], w[1] * hs[1][j]);
            acc[j] += fmaf(w[2], hs[2][j], fmaf(w[3], hs[3][j], t0));
        }
        // rotate pipeline registers
#pragma unroll
        for (int i = 0; i < 4; i++) { recA[i] = recB[i]; recB[i] = recC[i]; gA[i] = gB[i]; }
    }

    // self loop: edge_attr = mean of incoming attrs (all lanes hold full es[])
    {
        float inv_deg = 1.f / fmaxf((float)deg, 1.f);
        float p = 0.f;
#pragma unroll
        for (int j = 0; j < 4; j++) {
            float v = hli[j] + hrd[j];
#pragma unroll
            for (int k = 0; k < EDIM; k++) v = fmaf(es[k] * inv_deg, we[k][j], v);
            v = (v > 0.f) ? v : NEG * v;
            p = fmaf(v, av[j], p);
        }
#pragma unroll
        for (int d = 1; d < 64; d <<= 1) p += __shfl_xor(p, d);
        float w = __expf(p);
        denom += w;
#pragma unroll
        for (int j = 0; j < 4; j++) acc[j] = fmaf(w, hli[j], acc[j]);
    }

    float inv = 1.f / denom;
    t = *(const float4*)&bias[cb];
    float o[4];
    o[0] = acc[0] * inv + t.x;
    o[1] = acc[1] * inv + t.y;
    o[2] = acc[2] * inv + t.z;
    o[3] = acc[3] * inv + t.w;

    float s = o[0] + o[1] + o[2] + o[3];
#pragma unroll
    for (int d = 1; d < 64; d <<= 1) s += __shfl_xor(s, d);
    float mu = s * (1.f / 256.f);
    float vs = 0.f;
#pragma unroll
    for (int j = 0; j < 4; j++) { float dd = o[j] - mu; vs += dd * dd; }
#pragma unroll
    for (int d = 1; d < 64; d <<= 1) vs += __shfl_xor(vs, d);
    float rstd = rsqrtf(vs * (1.f / 256.f) + LN_EPS);

    float4 w4 = *(const float4*)&lnw[cb];
    float4 b4 = *(const float4*)&lnb[cb];
    ushort4 outv;
    outv.x = f2bu(fmaxf((o[0] - mu) * rstd * w4.x + b4.x, 0.f));
    outv.y = f2bu(fmaxf((o[1] - mu) * rstd * w4.y + b4.y, 0.f));
    outv.z = f2bu(fmaxf((o[2] - mu) * rstd * w4.z + b4.z, 0.f));
    outv.w = f2bu(fmaxf((o[3] - mu) * rstd * w4.w + b4.w, 0.f));
    *(ushort4*)&hout[(size_t)node * H + cb] = outv;
}

// ---------------------------------------------------------------------------
// Global mean pool per graph (batch sorted): one block per graph.
// ---------------------------------------------------------------------------
__global__ __launch_bounds__(256) void k_pool(const float* __restrict__ hf,
                                              const int* __restrict__ batch,
                                              float* __restrict__ out, int N) {
    __shared__ int s_lo, s_hi;
    int g = blockIdx.x, c = threadIdx.x;
    if (c == 0) {
        int lo = 0, hi = N;
        while (lo < hi) { int mid = (lo + hi) >> 1; if (batch[mid] < g) lo = mid + 1; else hi = mid; }
        s_lo = lo;
    }
    if (c == 1) {
        int lo = 0, hi = N;
        while (lo < hi) { int mid = (lo + hi) >> 1; if (batch[mid] < g + 1) lo = mid + 1; else hi = mid; }
        s_hi = lo;
    }
    __syncthreads();
    int lo = s_lo, hi = s_hi;
    float s = 0.f;
    for (int n = lo; n < hi; n++) s += hf[(size_t)n * H + c];
    float cnt = fmaxf((float)(hi - lo), 1.f);
    out[g * H + c] = s / cnt;
}

// ---------------------------------------------------------------------------
extern "C" void kernel_launch(void* const* d_in, const int* in_sizes, int n_in,
                              void* d_out, int out_size, void* d_ws, size_t ws_size,
                              hipStream_t stream) {
    const float* x        = (const float*)d_in[0];
    const int*   ei       = (const int*)d_in[1];
    const float* eattr    = (const float*)d_in[2];
    const int*   batch    = (const int*)d_in[3];
    const float* W_l0     = (const float*)d_in[4];
    const float* W_r0     = (const float*)d_in[5];
    const float* W_l      = (const float*)d_in[6];
    const float* W_r      = (const float*)d_in[7];
    const float* b_l      = (const float*)d_in[8];
    const float* b_r      = (const float*)d_in[9];
    const float* W_e      = (const float*)d_in[10];
    const float* att      = (const float*)d_in[11];
    const float* bias     = (const float*)d_in[12];
    const float* ln_w     = (const float*)d_in[13];
    const float* ln_b     = (const float*)d_in[14];
    const float* lin_W    = (const float*)d_in[15];
    const float* lin_b    = (const float*)d_in[16];

    const int N = in_sizes[0] / 23;          // 20000
    const int E = in_sizes[1] / 2;           // 320000
    const int G = out_size / H;              // 64
    const int L = 4;

    // workspace layout
    char* p = (char*)d_ws;
    float* hr = (float*)p;                        p += (size_t)N * H * 4;   // hr; reused as final f32 h
    int4* erec = (int4*)p;                        p += (size_t)E * 16;
    unsigned short* hlb = (unsigned short*)p;     p += (size_t)N * H * 2;
    unsigned short* hb  = (unsigned short*)p;     p += (size_t)NPAD * H * 2;
    __hip_bfloat16* xb  = (__hip_bfloat16*)p;     p += (size_t)NPAD * 32 * 2;
    __hip_bfloat16* w0t = (__hip_bfloat16*)p;     p += (size_t)2 * 256 * 32 * 2;
    __hip_bfloat16* wbig = (__hip_bfloat16*)p;    p += (size_t)7 * 65536 * 2;
    int* deg      = (int*)p;                      p += (size_t)N * 4;
    int* row_ptr  = (int*)p;                      p += (size_t)(N + 1) * 4;
    int* cursor   = (int*)p;                      p += (size_t)N * 4;

    __hip_bfloat16* Wl0t = w0t;
    __hip_bfloat16* Wr0t = w0t + 8192;
    __hip_bfloat16* Wlt  = wbig;
    __hip_bfloat16* Wrt  = wbig + (size_t)3 * 65536;
    __hip_bfloat16* linWt = wbig + (size_t)6 * 65536;

    hipMemsetAsync(deg, 0, (size_t)N * sizeof(int), stream);
    hipMemsetAsync(hb + (size_t)N * H, 0, (size_t)(NPAD - N) * H * 2, stream);

    int tb = 256;
    k_conv_x<<<(NPAD * 32 + tb - 1) / tb, tb, 0, stream>>>(x, xb, N);
    k_conv_w0<<<(2 * 256 * 32 + tb - 1) / tb, tb, 0, stream>>>(W_l0, W_r0, w0t);
    k_conv_w<<<(7 * 65536 + tb - 1) / tb, tb, 0, stream>>>(W_l, W_r, lin_W, wbig);

    k_edge_hist<<<(E + tb - 1) / tb, tb, 0, stream>>>(ei, deg, E);
    k_scan<<<1, 1024, 0, stream>>>(deg, row_ptr, cursor, N, E);
    k_scatter<<<(E + tb - 1) / tb, tb, 0, stream>>>(ei, eattr, cursor, erec, E);

    dim3 gdual(4, NPAD / 128), gsingle(2, NPAD / 128), blk(256);

    for (int l = 0; l < L; l++) {
        const __hip_bfloat16* A  = (l == 0) ? xb : (const __hip_bfloat16*)hb;
        const __hip_bfloat16* Wl = (l == 0) ? Wl0t : (Wlt + (size_t)(l - 1) * 65536);
        const __hip_bfloat16* Wr = (l == 0) ? Wr0t : (Wrt + (size_t)(l - 1) * 65536);
        if (l == 0)
            k_gemm_mfma<32><<<gdual, blk, 0, stream>>>(A, N, Wl, b_l + l * H, nullptr, hlb,
                                                       Wr, b_r + l * H, hr);
        else
            k_gemm_mfma<256><<<gdual, blk, 0, stream>>>(A, N, Wl, b_l + l * H, nullptr, hlb,
                                                        Wr, b_r + l * H, hr);
        k_gat<<<(N + 3) / 4, 256, 0, stream>>>(hlb, hr, row_ptr, erec,
                                               W_e + (size_t)l * EDIM * H, att + l * H,
                                               bias + l * H, ln_w + l * H, ln_b + l * H, hb, N);
    }

    // final projection (f32 out into hr buffer), then pool
    k_gemm_mfma<256><<<gsingle, blk, 0, stream>>>((const __hip_bfloat16*)hb, N, linWt, lin_b,
                                                  hr, nullptr, nullptr, nullptr, nullptr);
    k_pool<<<G, 256, 0, stream>>>(hr, batch, (float*)d_out, N);
}

// Round 5
// 666.371 us; speedup vs baseline: 1.1510x; 1.1510x over previous
//
#include <hip/hip_runtime.h>
#include <hip/hip_bf16.h>
#include <math.h>

#define H 256
#define EDIM 6
#define NEG 0.2f
#define LN_EPS 1e-5f
#define NPAD 20096   // 157 * 128

typedef __bf16 bf16x8 __attribute__((ext_vector_type(8)));
typedef float  floatx4 __attribute__((ext_vector_type(4)));

__device__ __forceinline__ unsigned short f2bu(float f) {
    __hip_bfloat16 h = __float2bfloat16(f);
    return *(unsigned short*)&h;
}

// ---------------------------------------------------------------------------
// CSR build
// ---------------------------------------------------------------------------
__global__ void k_edge_hist(const int* __restrict__ ei, int* __restrict__ deg, int E) {
    int e = blockIdx.x * blockDim.x + threadIdx.x;
    if (e >= E) return;
    atomicAdd(&deg[ei[E + e]], 1);
}

__global__ void k_scan(const int* __restrict__ deg, int* __restrict__ row_ptr,
                       int* __restrict__ cursor, int N, int E) {
    __shared__ int wsum[16];
    __shared__ int wpre[16];
    __shared__ int s_carry;
    int tid = threadIdx.x;
    int lane = tid & 63, wv = tid >> 6;
    if (tid == 0) s_carry = 0;
    __syncthreads();
    for (int base = 0; base < N; base += 1024) {
        int i = base + tid;
        int v = (i < N) ? deg[i] : 0;
        int x = v;
#pragma unroll
        for (int d = 1; d < 64; d <<= 1) {
            int y = __shfl_up(x, d);
            if (lane >= d) x += y;
        }
        if (lane == 63) wsum[wv] = x;
        __syncthreads();
        int total = 0;
        if (tid == 0) {
            int a = 0;
            for (int w = 0; w < 16; w++) { wpre[w] = a; a += wsum[w]; }
            total = a;
        }
        __syncthreads();
        int excl = s_carry + wpre[wv] + (x - v);
        if (i < N) { row_ptr[i] = excl; cursor[i] = excl; }
        __syncthreads();
        if (tid == 0) s_carry += total;
        __syncthreads();
    }
    if (tid == 0) row_ptr[N] = E;
}

// 32B edge record: {src_byte_off (as float bits), ea0..ea5, pad}
__global__ void k_scatter(const int* __restrict__ ei, const float* __restrict__ eattr,
                          int* __restrict__ cursor, float4* __restrict__ erec, int E) {
    int e = blockIdx.x * blockDim.x + threadIdx.x;
    if (e >= E) return;
    int s = ei[e], d = ei[E + e];
    int pos = atomicAdd(&cursor[d], 1);
    float4 ra, rb;
    ra.x = __int_as_float(s << 10);   // byte offset into fp32 [N,256] row
    ra.y = eattr[e * EDIM + 0];
    ra.z = eattr[e * EDIM + 1];
    ra.w = eattr[e * EDIM + 2];
    rb.x = eattr[e * EDIM + 3];
    rb.y = eattr[e * EDIM + 4];
    rb.z = eattr[e * EDIM + 5];
    rb.w = 0.f;
    erec[(size_t)pos * 2]     = ra;
    erec[(size_t)pos * 2 + 1] = rb;
}

// loop_attr[node][0..5] = mean of incoming edge attrs (layer-invariant)
__global__ __launch_bounds__(256) void k_loop_mean(const int* __restrict__ row_ptr,
                                                   const float4* __restrict__ erec,
                                                   float* __restrict__ loop_attr, int N) {
    int wv = threadIdx.x >> 6, lane = threadIdx.x & 63;
    int node = blockIdx.x * 4 + wv;
    if (node >= N) return;
    int e0 = row_ptr[node], e1 = row_ptr[node + 1];
    float es[6] = {0.f, 0.f, 0.f, 0.f, 0.f, 0.f};
    for (int e = e0 + lane; e < e1; e += 64) {
        float4 ra = erec[(size_t)e * 2];
        float4 rb = erec[(size_t)e * 2 + 1];
        es[0] += ra.y; es[1] += ra.z; es[2] += ra.w;
        es[3] += rb.x; es[4] += rb.y; es[5] += rb.z;
    }
#pragma unroll
    for (int d = 1; d < 64; d <<= 1) {
#pragma unroll
        for (int k = 0; k < 6; k++) es[k] += __shfl_xor(es[k], d);
    }
    if (lane == 0) {
        float inv = 1.f / fmaxf((float)(e1 - e0), 1.f);
        float4 a, b;
        a.x = es[0] * inv; a.y = es[1] * inv; a.z = es[2] * inv; a.w = es[3] * inv;
        b.x = es[4] * inv; b.y = es[5] * inv; b.z = 0.f; b.w = 0.f;
        *(float4*)&loop_attr[(size_t)node * 8]     = a;
        *(float4*)&loop_attr[(size_t)node * 8 + 4] = b;
    }
}

// ---------------------------------------------------------------------------
// Weight conversions to transposed bf16 [c][k]
// ---------------------------------------------------------------------------
__global__ void k_conv_x(const float* __restrict__ x, __hip_bfloat16* __restrict__ xb, int N) {
    int idx = blockIdx.x * blockDim.x + threadIdx.x;
    if (idx >= NPAD * 32) return;
    int r = idx >> 5, k = idx & 31;
    float v = (r < N && k < 23) ? x[r * 23 + k] : 0.f;
    xb[idx] = __float2bfloat16(v);
}

__global__ void k_conv_w0(const float* __restrict__ Wl0, const float* __restrict__ Wr0,
                          __hip_bfloat16* __restrict__ out) {
    int idx = blockIdx.x * blockDim.x + threadIdx.x;
    if (idx >= 2 * 256 * 32) return;
    int mat = idx >> 13, rem = idx & 8191;
    int c = rem >> 5, k = rem & 31;
    const float* W = mat ? Wr0 : Wl0;
    float v = (k < 23) ? W[k * 256 + c] : 0.f;
    out[idx] = __float2bfloat16(v);
}

__global__ void k_conv_w(const float* __restrict__ Wl, const float* __restrict__ Wr,
                         const float* __restrict__ lin, __hip_bfloat16* __restrict__ out) {
    int idx = blockIdx.x * blockDim.x + threadIdx.x;
    if (idx >= 7 * 65536) return;
    int mat = idx >> 16, rem = idx & 65535;
    int c = rem >> 8, k = rem & 255;
    const float* W = (mat < 3) ? (Wl + (size_t)mat * 65536)
                   : (mat < 6) ? (Wr + (size_t)(mat - 3) * 65536)
                   : lin;
    out[idx] = __float2bfloat16(W[k * 256 + c]);
}

// ---------------------------------------------------------------------------
// MFMA dual GEMM, K compile-time. f32 outputs.
// ---------------------------------------------------------------------------
template<int K>
__global__ __launch_bounds__(256) void k_gemm_mfma(
    const __hip_bfloat16* __restrict__ A, int N,
    const __hip_bfloat16* __restrict__ Wt1, const float* __restrict__ b1,
    float* __restrict__ C1,
    const __hip_bfloat16* __restrict__ Wt2, const float* __restrict__ b2,
    float* __restrict__ C2) {
    int tid = threadIdx.x;
    int wv = tid >> 6, lane = tid & 63;
    int quad = lane >> 4, l16 = lane & 15;
    int mat = blockIdx.x >> 1;
    int c0 = (blockIdx.x & 1) * 128;
    int r0 = blockIdx.y * 128;
    const __hip_bfloat16* Wt = mat ? Wt2 : Wt1;
    const float* bv = mat ? b2 : b1;
    float* C = mat ? C2 : C1;
    int wm = wv >> 1, wn = wv & 1;
    int rbase = r0 + wm * 64;
    int cbase = c0 + wn * 64;

    floatx4 acc[4][4] = {};
    const __bf16* Ab = (const __bf16*)A;
    const __bf16* Bb = (const __bf16*)Wt;
#pragma unroll 2
    for (int k0 = 0; k0 < K; k0 += 32) {
        bf16x8 a[4], b[4];
        const __bf16* Ap = Ab + (size_t)(rbase + l16) * K + k0 + quad * 8;
#pragma unroll
        for (int mi = 0; mi < 4; mi++)
            a[mi] = *(const bf16x8*)(Ap + (size_t)mi * 16 * K);
        const __bf16* Bp = Bb + (size_t)(cbase + l16) * K + k0 + quad * 8;
#pragma unroll
        for (int ni = 0; ni < 4; ni++)
            b[ni] = *(const bf16x8*)(Bp + (size_t)ni * 16 * K);
#pragma unroll
        for (int mi = 0; mi < 4; mi++)
#pragma unroll
            for (int ni = 0; ni < 4; ni++)
                acc[mi][ni] = __builtin_amdgcn_mfma_f32_16x16x32_bf16(a[mi], b[ni], acc[mi][ni], 0, 0, 0);
    }
#pragma unroll
    for (int ni = 0; ni < 4; ni++) {
        int c = cbase + ni * 16 + l16;
        float bb = bv[c];
#pragma unroll
        for (int mi = 0; mi < 4; mi++) {
#pragma unroll
            for (int r = 0; r < 4; r++) {
                int gr = rbase + mi * 16 + quad * 4 + r;
                if (gr < N) C[(size_t)gr * H + c] = acc[mi][ni][r] + bb;
            }
        }
    }
}

// ---------------------------------------------------------------------------
// Fused GATv2 edge pass v4: one wave per node, 32B fp32 edge records, fp32
// gathers (bytes are free -- latency/VALU bound), flat softmax, select-free
// main loop + predicated tail, precomputed loop_attr, fused LN+ReLU, bf16 out.
// ---------------------------------------------------------------------------
__global__ __launch_bounds__(256) void k_gat(
    const float* __restrict__ hlf, const float* __restrict__ hr,
    const int* __restrict__ row_ptr, const float4* __restrict__ erec,
    const float* __restrict__ loop_attr,
    const float* __restrict__ We, const float* __restrict__ attv,
    const float* __restrict__ bias, const float* __restrict__ lnw,
    const float* __restrict__ lnb, unsigned short* __restrict__ hout, int N) {
    int wv = threadIdx.x >> 6;
    int lane = threadIdx.x & 63;
    int node = blockIdx.x * 4 + wv;
    if (node >= N) return;
    int cb = lane * 4;
    int cb4 = cb * 4;                 // byte offset of this lane's channel block
    const char* hbase = (const char*)hlf;

    float we[EDIM][4];
#pragma unroll
    for (int k = 0; k < EDIM; k++) {
        float4 t = *(const float4*)&We[k * H + cb];
        we[k][0] = t.x; we[k][1] = t.y; we[k][2] = t.z; we[k][3] = t.w;
    }
    float4 t;
    t = *(const float4*)&attv[cb];
    float av[4] = {t.x, t.y, t.z, t.w};
    t = *(const float4*)&hr[(size_t)node * H + cb];
    float hrd[4] = {t.x, t.y, t.z, t.w};
    t = *(const float4*)&hlf[(size_t)node * H + cb];
    float hli[4] = {t.x, t.y, t.z, t.w};

    float denom = 0.f;
    float acc[4] = {0.f, 0.f, 0.f, 0.f};

    int e0 = row_ptr[node], e1 = row_ptr[node + 1];
    int deg = e1 - e0;
    int gfull = deg >> 2;

    for (int g = 0; g < gfull; g++) {
        int base = e0 + g * 4;
        float te[4][4], hs[4][4], p[4];
#pragma unroll
        for (int i = 0; i < 4; i++) {
            float4 ra = erec[(size_t)(base + i) * 2];
            float4 rb = erec[(size_t)(base + i) * 2 + 1];
            float4 h4 = *(const float4*)(hbase + (__float_as_int(ra.x) + cb4));
            hs[i][0] = h4.x; hs[i][1] = h4.y; hs[i][2] = h4.z; hs[i][3] = h4.w;
#pragma unroll
            for (int j = 0; j < 4; j++) {
                float tt = hrd[j];
                tt = fmaf(ra.y, we[0][j], tt);
                tt = fmaf(ra.z, we[1][j], tt);
                tt = fmaf(ra.w, we[2][j], tt);
                tt = fmaf(rb.x, we[3][j], tt);
                tt = fmaf(rb.y, we[4][j], tt);
                tt = fmaf(rb.z, we[5][j], tt);
                te[i][j] = tt;
            }
        }
#pragma unroll
        for (int i = 0; i < 4; i++) {
            float pp = 0.f;
#pragma unroll
            for (int j = 0; j < 4; j++) {
                float v = hs[i][j] + te[i][j];
                v = fmaxf(v, NEG * v);        // leaky_relu, 2 ops
                pp = fmaf(v, av[j], pp);
            }
            p[i] = pp;
        }
#pragma unroll
        for (int d = 1; d < 64; d <<= 1) {
#pragma unroll
            for (int i = 0; i < 4; i++) p[i] += __shfl_xor(p[i], d);
        }
        float w0 = __expf(p[0]), w1 = __expf(p[1]);
        float w2 = __expf(p[2]), w3 = __expf(p[3]);
        denom += (w0 + w1) + (w2 + w3);
#pragma unroll
        for (int j = 0; j < 4; j++)
            acc[j] += fmaf(w0, hs[0][j], fmaf(w1, hs[1][j], fmaf(w2, hs[2][j], w3 * hs[3][j])));
    }

    int trem = deg & 3;
    if (trem) {
        int base = e0 + gfull * 4;
        float te[4][4], hs[4][4], p[4];
#pragma unroll
        for (int i = 0; i < 4; i++) {
            int idx = (i < trem) ? (base + i) : base;
            float4 ra = erec[(size_t)idx * 2];
            float4 rb = erec[(size_t)idx * 2 + 1];
            float4 h4 = *(const float4*)(hbase + (__float_as_int(ra.x) + cb4));
            hs[i][0] = h4.x; hs[i][1] = h4.y; hs[i][2] = h4.z; hs[i][3] = h4.w;
#pragma unroll
            for (int j = 0; j < 4; j++) {
                float tt = hrd[j];
                tt = fmaf(ra.y, we[0][j], tt);
                tt = fmaf(ra.z, we[1][j], tt);
                tt = fmaf(ra.w, we[2][j], tt);
                tt = fmaf(rb.x, we[3][j], tt);
                tt = fmaf(rb.y, we[4][j], tt);
                tt = fmaf(rb.z, we[5][j], tt);
                te[i][j] = tt;
            }
        }
#pragma unroll
        for (int i = 0; i < 4; i++) {
            float pp = 0.f;
#pragma unroll
            for (int j = 0; j < 4; j++) {
                float v = hs[i][j] + te[i][j];
                v = fmaxf(v, NEG * v);
                pp = fmaf(v, av[j], pp);
            }
            p[i] = pp;
        }
#pragma unroll
        for (int d = 1; d < 64; d <<= 1) {
#pragma unroll
            for (int i = 0; i < 4; i++) p[i] += __shfl_xor(p[i], d);
        }
        float w[4];
#pragma unroll
        for (int i = 0; i < 4; i++)
            w[i] = (i < trem) ? __expf(p[i]) : 0.f;
        denom += (w[0] + w[1]) + (w[2] + w[3]);
#pragma unroll
        for (int j = 0; j < 4; j++)
            acc[j] += fmaf(w[0], hs[0][j], fmaf(w[1], hs[1][j], fmaf(w[2], hs[2][j], w[3] * hs[3][j])));
    }

    // self loop with precomputed mean attrs
    {
        float4 la0 = *(const float4*)&loop_attr[(size_t)node * 8];
        float4 la1 = *(const float4*)&loop_attr[(size_t)node * 8 + 4];
        float p = 0.f;
#pragma unroll
        for (int j = 0; j < 4; j++) {
            float v = hli[j] + hrd[j];
            v = fmaf(la0.y, we[1][j], fmaf(la0.x, we[0][j], v));
            v = fmaf(la0.w, we[3][j], fmaf(la0.z, we[2][j], v));
            v = fmaf(la1.y, we[5][j], fmaf(la1.x, we[4][j], v));
            v = fmaxf(v, NEG * v);
            p = fmaf(v, av[j], p);
        }
#pragma unroll
        for (int d = 1; d < 64; d <<= 1) p += __shfl_xor(p, d);
        float w = __expf(p);
        denom += w;
#pragma unroll
        for (int j = 0; j < 4; j++) acc[j] = fmaf(w, hli[j], acc[j]);
    }

    float inv = 1.f / denom;
    t = *(const float4*)&bias[cb];
    float o[4];
    o[0] = acc[0] * inv + t.x;
    o[1] = acc[1] * inv + t.y;
    o[2] = acc[2] * inv + t.z;
    o[3] = acc[3] * inv + t.w;

    float s = o[0] + o[1] + o[2] + o[3];
#pragma unroll
    for (int d = 1; d < 64; d <<= 1) s += __shfl_xor(s, d);
    float mu = s * (1.f / 256.f);
    float vs = 0.f;
#pragma unroll
    for (int j = 0; j < 4; j++) { float dd = o[j] - mu; vs += dd * dd; }
#pragma unroll
    for (int d = 1; d < 64; d <<= 1) vs += __shfl_xor(vs, d);
    float rstd = rsqrtf(vs * (1.f / 256.f) + LN_EPS);

    float4 w4 = *(const float4*)&lnw[cb];
    float4 b4 = *(const float4*)&lnb[cb];
    ushort4 outv;
    outv.x = f2bu(fmaxf((o[0] - mu) * rstd * w4.x + b4.x, 0.f));
    outv.y = f2bu(fmaxf((o[1] - mu) * rstd * w4.y + b4.y, 0.f));
    outv.z = f2bu(fmaxf((o[2] - mu) * rstd * w4.z + b4.z, 0.f));
    outv.w = f2bu(fmaxf((o[3] - mu) * rstd * w4.w + b4.w, 0.f));
    *(ushort4*)&hout[(size_t)node * H + cb] = outv;
}

// ---------------------------------------------------------------------------
// Global mean pool per graph (batch sorted): one block per graph.
// ---------------------------------------------------------------------------
__global__ __launch_bounds__(256) void k_pool(const float* __restrict__ hf,
                                              const int* __restrict__ batch,
                                              float* __restrict__ out, int N) {
    __shared__ int s_lo, s_hi;
    int g = blockIdx.x, c = threadIdx.x;
    if (c == 0) {
        int lo = 0, hi = N;
        while (lo < hi) { int mid = (lo + hi) >> 1; if (batch[mid] < g) lo = mid + 1; else hi = mid; }
        s_lo = lo;
    }
    if (c == 1) {
        int lo = 0, hi = N;
        while (lo < hi) { int mid = (lo + hi) >> 1; if (batch[mid] < g + 1) lo = mid + 1; else hi = mid; }
        s_hi = lo;
    }
    __syncthreads();
    int lo = s_lo, hi = s_hi;
    float s = 0.f;
    for (int n = lo; n < hi; n++) s += hf[(size_t)n * H + c];
    float cnt = fmaxf((float)(hi - lo), 1.f);
    out[g * H + c] = s / cnt;
}

// ---------------------------------------------------------------------------
extern "C" void kernel_launch(void* const* d_in, const int* in_sizes, int n_in,
                              void* d_out, int out_size, void* d_ws, size_t ws_size,
                              hipStream_t stream) {
    const float* x        = (const float*)d_in[0];
    const int*   ei       = (const int*)d_in[1];
    const float* eattr    = (const float*)d_in[2];
    const int*   batch    = (const int*)d_in[3];
    const float* W_l0     = (const float*)d_in[4];
    const float* W_r0     = (const float*)d_in[5];
    const float* W_l      = (const float*)d_in[6];
    const float* W_r      = (const float*)d_in[7];
    const float* b_l      = (const float*)d_in[8];
    const float* b_r      = (const float*)d_in[9];
    const float* W_e      = (const float*)d_in[10];
    const float* att      = (const float*)d_in[11];
    const float* bias     = (const float*)d_in[12];
    const float* ln_w     = (const float*)d_in[13];
    const float* ln_b     = (const float*)d_in[14];
    const float* lin_W    = (const float*)d_in[15];
    const float* lin_b    = (const float*)d_in[16];

    const int N = in_sizes[0] / 23;          // 20000
    const int E = in_sizes[1] / 2;           // 320000
    const int G = out_size / H;              // 64
    const int L = 4;

    // workspace layout
    char* p = (char*)d_ws;
    float* hlf = (float*)p;                       p += (size_t)N * H * 4;   // hl f32
    float* hr  = (float*)p;                       p += (size_t)N * H * 4;   // hr f32 / final h
    float4* erec = (float4*)p;                    p += (size_t)E * 32;
    unsigned short* hb = (unsigned short*)p;      p += (size_t)NPAD * H * 2;
    __hip_bfloat16* xb  = (__hip_bfloat16*)p;     p += (size_t)NPAD * 32 * 2;
    __hip_bfloat16* w0t = (__hip_bfloat16*)p;     p += (size_t)2 * 256 * 32 * 2;
    __hip_bfloat16* wbig = (__hip_bfloat16*)p;    p += (size_t)7 * 65536 * 2;
    float* loop_attr = (float*)p;                 p += (size_t)N * 8 * 4;
    int* deg      = (int*)p;                      p += (size_t)N * 4;
    int* row_ptr  = (int*)p;                      p += (size_t)(N + 1) * 4;
    int* cursor   = (int*)p;                      p += (size_t)N * 4;

    __hip_bfloat16* Wl0t = w0t;
    __hip_bfloat16* Wr0t = w0t + 8192;
    __hip_bfloat16* Wlt  = wbig;
    __hip_bfloat16* Wrt  = wbig + (size_t)3 * 65536;
    __hip_bfloat16* linWt = wbig + (size_t)6 * 65536;

    hipMemsetAsync(deg, 0, (size_t)N * sizeof(int), stream);
    hipMemsetAsync(hb + (size_t)N * H, 0, (size_t)(NPAD - N) * H * 2, stream);

    int tb = 256;
    k_conv_x<<<(NPAD * 32 + tb - 1) / tb, tb, 0, stream>>>(x, xb, N);
    k_conv_w0<<<(2 * 256 * 32 + tb - 1) / tb, tb, 0, stream>>>(W_l0, W_r0, w0t);
    k_conv_w<<<(7 * 65536 + tb - 1) / tb, tb, 0, stream>>>(W_l, W_r, lin_W, wbig);

    k_edge_hist<<<(E + tb - 1) / tb, tb, 0, stream>>>(ei, deg, E);
    k_scan<<<1, 1024, 0, stream>>>(deg, row_ptr, cursor, N, E);
    k_scatter<<<(E + tb - 1) / tb, tb, 0, stream>>>(ei, eattr, cursor, erec, E);
    k_loop_mean<<<(N + 3) / 4, 256, 0, stream>>>(row_ptr, erec, loop_attr, N);

    dim3 gdual(4, NPAD / 128), gsingle(2, NPAD / 128), blk(256);

    for (int l = 0; l < L; l++) {
        const __hip_bfloat16* A  = (l == 0) ? xb : (const __hip_bfloat16*)hb;
        const __hip_bfloat16* Wl = (l == 0) ? Wl0t : (Wlt + (size_t)(l - 1) * 65536);
        const __hip_bfloat16* Wr = (l == 0) ? Wr0t : (Wrt + (size_t)(l - 1) * 65536);
        if (l == 0)
            k_gemm_mfma<32><<<gdual, blk, 0, stream>>>(A, N, Wl, b_l + l * H, hlf,
                                                       Wr, b_r + l * H, hr);
        else
            k_gemm_mfma<256><<<gdual, blk, 0, stream>>>(A, N, Wl, b_l + l * H, hlf,
                                                        Wr, b_r + l * H, hr);
        k_gat<<<(N + 3) / 4, 256, 0, stream>>>(hlf, hr, row_ptr, erec, loop_attr,
                                               W_e + (size_t)l * EDIM * H, att + l * H,
                                               bias + l * H, ln_w + l * H, ln_b + l * H, hb, N);
    }

    // final projection (f32 out into hr), then pool
    k_gemm_mfma<256><<<gsingle, blk, 0, stream>>>((const __hip_bfloat16*)hb, N, linWt, lin_b,
                                                  hr, nullptr, nullptr, nullptr);
    k_pool<<<G, 256, 0, stream>>>(hr, batch, (float*)d_out, N);
}

// Round 6
// 596.592 us; speedup vs baseline: 1.2856x; 1.1170x over previous
//
#include <hip/hip_runtime.h>
#include <hip/hip_bf16.h>
#include <math.h>

#define H 256
#define EDIM 6
#define NEG 0.2f
#define LN_EPS 1e-5f
#define NPAD 20096   // 157 * 128

typedef __bf16 bf16x8 __attribute__((ext_vector_type(8)));
typedef float  floatx4 __attribute__((ext_vector_type(4)));

__device__ __forceinline__ float b2f(unsigned short u) {
    union { unsigned int i; float f; } v; v.i = ((unsigned int)u) << 16; return v.f;
}
__device__ __forceinline__ unsigned short f2bu(float f) {
    __hip_bfloat16 h = __float2bfloat16(f);
    return *(unsigned short*)&h;
}

// ---------------------------------------------------------------------------
// CSR build
// ---------------------------------------------------------------------------
__global__ void k_edge_hist(const int* __restrict__ ei, int* __restrict__ deg, int E) {
    int e = blockIdx.x * blockDim.x + threadIdx.x;
    if (e >= E) return;
    atomicAdd(&deg[ei[E + e]], 1);
}

__global__ void k_scan(const int* __restrict__ deg, int* __restrict__ row_ptr,
                       int* __restrict__ cursor, int N, int E) {
    __shared__ int wsum[16];
    __shared__ int wpre[16];
    __shared__ int s_carry;
    int tid = threadIdx.x;
    int lane = tid & 63, wv = tid >> 6;
    if (tid == 0) s_carry = 0;
    __syncthreads();
    for (int base = 0; base < N; base += 1024) {
        int i = base + tid;
        int v = (i < N) ? deg[i] : 0;
        int x = v;
#pragma unroll
        for (int d = 1; d < 64; d <<= 1) {
            int y = __shfl_up(x, d);
            if (lane >= d) x += y;
        }
        if (lane == 63) wsum[wv] = x;
        __syncthreads();
        int total = 0;
        if (tid == 0) {
            int a = 0;
            for (int w = 0; w < 16; w++) { wpre[w] = a; a += wsum[w]; }
            total = a;
        }
        __syncthreads();
        int excl = s_carry + wpre[wv] + (x - v);
        if (i < N) { row_ptr[i] = excl; cursor[i] = excl; }
        __syncthreads();
        if (tid == 0) s_carry += total;
        __syncthreads();
    }
    if (tid == 0) row_ptr[N] = E;
}

// 32B edge record: {src_byte_off (as float bits), ea0..ea5, pad}
__global__ void k_scatter(const int* __restrict__ ei, const float* __restrict__ eattr,
                          int* __restrict__ cursor, float4* __restrict__ erec, int E) {
    int e = blockIdx.x * blockDim.x + threadIdx.x;
    if (e >= E) return;
    int s = ei[e], d = ei[E + e];
    int pos = atomicAdd(&cursor[d], 1);
    float4 ra, rb;
    ra.x = __int_as_float(s << 10);   // byte offset into fp32 [N,256] row
    ra.y = eattr[e * EDIM + 0];
    ra.z = eattr[e * EDIM + 1];
    ra.w = eattr[e * EDIM + 2];
    rb.x = eattr[e * EDIM + 3];
    rb.y = eattr[e * EDIM + 4];
    rb.z = eattr[e * EDIM + 5];
    rb.w = 0.f;
    erec[(size_t)pos * 2]     = ra;
    erec[(size_t)pos * 2 + 1] = rb;
}

// loop_attr[node][0..5] = mean of incoming edge attrs (layer-invariant)
__global__ __launch_bounds__(256) void k_loop_mean(const int* __restrict__ row_ptr,
                                                   const float4* __restrict__ erec,
                                                   float* __restrict__ loop_attr, int N) {
    int wv = threadIdx.x >> 6, lane = threadIdx.x & 63;
    int node = blockIdx.x * 4 + wv;
    if (node >= N) return;
    int e0 = row_ptr[node], e1 = row_ptr[node + 1];
    float es[6] = {0.f, 0.f, 0.f, 0.f, 0.f, 0.f};
    for (int e = e0 + lane; e < e1; e += 64) {
        float4 ra = erec[(size_t)e * 2];
        float4 rb = erec[(size_t)e * 2 + 1];
        es[0] += ra.y; es[1] += ra.z; es[2] += ra.w;
        es[3] += rb.x; es[4] += rb.y; es[5] += rb.z;
    }
#pragma unroll
    for (int d = 1; d < 64; d <<= 1) {
#pragma unroll
        for (int k = 0; k < 6; k++) es[k] += __shfl_xor(es[k], d);
    }
    if (lane == 0) {
        float inv = 1.f / fmaxf((float)(e1 - e0), 1.f);
        float4 a, b;
        a.x = es[0] * inv; a.y = es[1] * inv; a.z = es[2] * inv; a.w = es[3] * inv;
        b.x = es[4] * inv; b.y = es[5] * inv; b.z = 0.f; b.w = 0.f;
        *(float4*)&loop_attr[(size_t)node * 8]     = a;
        *(float4*)&loop_attr[(size_t)node * 8 + 4] = b;
    }
}

// ---------------------------------------------------------------------------
// Weight conversions to transposed bf16 [c][k]
// ---------------------------------------------------------------------------
__global__ void k_conv_x(const float* __restrict__ x, __hip_bfloat16* __restrict__ xb, int N) {
    int idx = blockIdx.x * blockDim.x + threadIdx.x;
    if (idx >= NPAD * 32) return;
    int r = idx >> 5, k = idx & 31;
    float v = (r < N && k < 23) ? x[r * 23 + k] : 0.f;
    xb[idx] = __float2bfloat16(v);
}

__global__ void k_conv_w0(const float* __restrict__ Wl0, const float* __restrict__ Wr0,
                          __hip_bfloat16* __restrict__ out) {
    int idx = blockIdx.x * blockDim.x + threadIdx.x;
    if (idx >= 2 * 256 * 32) return;
    int mat = idx >> 13, rem = idx & 8191;
    int c = rem >> 5, k = rem & 31;
    const float* W = mat ? Wr0 : Wl0;
    float v = (k < 23) ? W[k * 256 + c] : 0.f;
    out[idx] = __float2bfloat16(v);
}

__global__ void k_conv_w(const float* __restrict__ Wl, const float* __restrict__ Wr,
                         __hip_bfloat16* __restrict__ out) {
    int idx = blockIdx.x * blockDim.x + threadIdx.x;
    if (idx >= 6 * 65536) return;
    int mat = idx >> 16, rem = idx & 65535;
    int c = rem >> 8, k = rem & 255;
    const float* W = (mat < 3) ? (Wl + (size_t)mat * 65536)
                   : (Wr + (size_t)(mat - 3) * 65536);
    out[idx] = __float2bfloat16(W[k * 256 + c]);
}

// ---------------------------------------------------------------------------
// MFMA dual GEMM, K compile-time. f32 outputs.
// ---------------------------------------------------------------------------
template<int K>
__global__ __launch_bounds__(256) void k_gemm_mfma(
    const __hip_bfloat16* __restrict__ A, int N,
    const __hip_bfloat16* __restrict__ Wt1, const float* __restrict__ b1,
    float* __restrict__ C1,
    const __hip_bfloat16* __restrict__ Wt2, const float* __restrict__ b2,
    float* __restrict__ C2) {
    int tid = threadIdx.x;
    int wv = tid >> 6, lane = tid & 63;
    int quad = lane >> 4, l16 = lane & 15;
    int mat = blockIdx.x >> 1;
    int c0 = (blockIdx.x & 1) * 128;
    int r0 = blockIdx.y * 128;
    const __hip_bfloat16* Wt = mat ? Wt2 : Wt1;
    const float* bv = mat ? b2 : b1;
    float* C = mat ? C2 : C1;
    int wm = wv >> 1, wn = wv & 1;
    int rbase = r0 + wm * 64;
    int cbase = c0 + wn * 64;

    floatx4 acc[4][4] = {};
    const __bf16* Ab = (const __bf16*)A;
    const __bf16* Bb = (const __bf16*)Wt;
#pragma unroll 2
    for (int k0 = 0; k0 < K; k0 += 32) {
        bf16x8 a[4], b[4];
        const __bf16* Ap = Ab + (size_t)(rbase + l16) * K + k0 + quad * 8;
#pragma unroll
        for (int mi = 0; mi < 4; mi++)
            a[mi] = *(const bf16x8*)(Ap + (size_t)mi * 16 * K);
        const __bf16* Bp = Bb + (size_t)(cbase + l16) * K + k0 + quad * 8;
#pragma unroll
        for (int ni = 0; ni < 4; ni++)
            b[ni] = *(const bf16x8*)(Bp + (size_t)ni * 16 * K);
#pragma unroll
        for (int mi = 0; mi < 4; mi++)
#pragma unroll
            for (int ni = 0; ni < 4; ni++)
                acc[mi][ni] = __builtin_amdgcn_mfma_f32_16x16x32_bf16(a[mi], b[ni], acc[mi][ni], 0, 0, 0);
    }
#pragma unroll
    for (int ni = 0; ni < 4; ni++) {
        int c = cbase + ni * 16 + l16;
        float bb = bv[c];
#pragma unroll
        for (int mi = 0; mi < 4; mi++) {
#pragma unroll
            for (int r = 0; r < 4; r++) {
                int gr = rbase + mi * 16 + quad * 4 + r;
                if (gr < N) C[(size_t)gr * H + c] = acc[mi][ni][r] + bb;
            }
        }
    }
}

// ---------------------------------------------------------------------------
// Fused GATv2 edge pass v4 (unchanged from r5 winner)
// ---------------------------------------------------------------------------
__global__ __launch_bounds__(256) void k_gat(
    const float* __restrict__ hlf, const float* __restrict__ hr,
    const int* __restrict__ row_ptr, const float4* __restrict__ erec,
    const float* __restrict__ loop_attr,
    const float* __restrict__ We, const float* __restrict__ attv,
    const float* __restrict__ bias, const float* __restrict__ lnw,
    const float* __restrict__ lnb, unsigned short* __restrict__ hout, int N) {
    int wv = threadIdx.x >> 6;
    int lane = threadIdx.x & 63;
    int node = blockIdx.x * 4 + wv;
    if (node >= N) return;
    int cb = lane * 4;
    int cb4 = cb * 4;
    const char* hbase = (const char*)hlf;

    float we[EDIM][4];
#pragma unroll
    for (int k = 0; k < EDIM; k++) {
        float4 t = *(const float4*)&We[k * H + cb];
        we[k][0] = t.x; we[k][1] = t.y; we[k][2] = t.z; we[k][3] = t.w;
    }
    float4 t;
    t = *(const float4*)&attv[cb];
    float av[4] = {t.x, t.y, t.z, t.w};
    t = *(const float4*)&hr[(size_t)node * H + cb];
    float hrd[4] = {t.x, t.y, t.z, t.w};
    t = *(const float4*)&hlf[(size_t)node * H + cb];
    float hli[4] = {t.x, t.y, t.z, t.w};

    float denom = 0.f;
    float acc[4] = {0.f, 0.f, 0.f, 0.f};

    int e0 = row_ptr[node], e1 = row_ptr[node + 1];
    int deg = e1 - e0;
    int gfull = deg >> 2;

    for (int g = 0; g < gfull; g++) {
        int base = e0 + g * 4;
        float te[4][4], hs[4][4], p[4];
#pragma unroll
        for (int i = 0; i < 4; i++) {
            float4 ra = erec[(size_t)(base + i) * 2];
            float4 rb = erec[(size_t)(base + i) * 2 + 1];
            float4 h4 = *(const float4*)(hbase + (__float_as_int(ra.x) + cb4));
            hs[i][0] = h4.x; hs[i][1] = h4.y; hs[i][2] = h4.z; hs[i][3] = h4.w;
#pragma unroll
            for (int j = 0; j < 4; j++) {
                float tt = hrd[j];
                tt = fmaf(ra.y, we[0][j], tt);
                tt = fmaf(ra.z, we[1][j], tt);
                tt = fmaf(ra.w, we[2][j], tt);
                tt = fmaf(rb.x, we[3][j], tt);
                tt = fmaf(rb.y, we[4][j], tt);
                tt = fmaf(rb.z, we[5][j], tt);
                te[i][j] = tt;
            }
        }
#pragma unroll
        for (int i = 0; i < 4; i++) {
            float pp = 0.f;
#pragma unroll
            for (int j = 0; j < 4; j++) {
                float v = hs[i][j] + te[i][j];
                v = fmaxf(v, NEG * v);
                pp = fmaf(v, av[j], pp);
            }
            p[i] = pp;
        }
#pragma unroll
        for (int d = 1; d < 64; d <<= 1) {
#pragma unroll
            for (int i = 0; i < 4; i++) p[i] += __shfl_xor(p[i], d);
        }
        float w0 = __expf(p[0]), w1 = __expf(p[1]);
        float w2 = __expf(p[2]), w3 = __expf(p[3]);
        denom += (w0 + w1) + (w2 + w3);
#pragma unroll
        for (int j = 0; j < 4; j++)
            acc[j] += fmaf(w0, hs[0][j], fmaf(w1, hs[1][j], fmaf(w2, hs[2][j], w3 * hs[3][j])));
    }

    int trem = deg & 3;
    if (trem) {
        int base = e0 + gfull * 4;
        float te[4][4], hs[4][4], p[4];
#pragma unroll
        for (int i = 0; i < 4; i++) {
            int idx = (i < trem) ? (base + i) : base;
            float4 ra = erec[(size_t)idx * 2];
            float4 rb = erec[(size_t)idx * 2 + 1];
            float4 h4 = *(const float4*)(hbase + (__float_as_int(ra.x) + cb4));
            hs[i][0] = h4.x; hs[i][1] = h4.y; hs[i][2] = h4.z; hs[i][3] = h4.w;
#pragma unroll
            for (int j = 0; j < 4; j++) {
                float tt = hrd[j];
                tt = fmaf(ra.y, we[0][j], tt);
                tt = fmaf(ra.z, we[1][j], tt);
                tt = fmaf(ra.w, we[2][j], tt);
                tt = fmaf(rb.x, we[3][j], tt);
                tt = fmaf(rb.y, we[4][j], tt);
                tt = fmaf(rb.z, we[5][j], tt);
                te[i][j] = tt;
            }
        }
#pragma unroll
        for (int i = 0; i < 4; i++) {
            float pp = 0.f;
#pragma unroll
            for (int j = 0; j < 4; j++) {
                float v = hs[i][j] + te[i][j];
                v = fmaxf(v, NEG * v);
                pp = fmaf(v, av[j], pp);
            }
            p[i] = pp;
        }
#pragma unroll
        for (int d = 1; d < 64; d <<= 1) {
#pragma unroll
            for (int i = 0; i < 4; i++) p[i] += __shfl_xor(p[i], d);
        }
        float w[4];
#pragma unroll
        for (int i = 0; i < 4; i++)
            w[i] = (i < trem) ? __expf(p[i]) : 0.f;
        denom += (w[0] + w[1]) + (w[2] + w[3]);
#pragma unroll
        for (int j = 0; j < 4; j++)
            acc[j] += fmaf(w[0], hs[0][j], fmaf(w[1], hs[1][j], fmaf(w[2], hs[2][j], w[3] * hs[3][j])));
    }

    // self loop with precomputed mean attrs
    {
        float4 la0 = *(const float4*)&loop_attr[(size_t)node * 8];
        float4 la1 = *(const float4*)&loop_attr[(size_t)node * 8 + 4];
        float p = 0.f;
#pragma unroll
        for (int j = 0; j < 4; j++) {
            float v = hli[j] + hrd[j];
            v = fmaf(la0.y, we[1][j], fmaf(la0.x, we[0][j], v));
            v = fmaf(la0.w, we[3][j], fmaf(la0.z, we[2][j], v));
            v = fmaf(la1.y, we[5][j], fmaf(la1.x, we[4][j], v));
            v = fmaxf(v, NEG * v);
            p = fmaf(v, av[j], p);
        }
#pragma unroll
        for (int d = 1; d < 64; d <<= 1) p += __shfl_xor(p, d);
        float w = __expf(p);
        denom += w;
#pragma unroll
        for (int j = 0; j < 4; j++) acc[j] = fmaf(w, hli[j], acc[j]);
    }

    float inv = 1.f / denom;
    t = *(const float4*)&bias[cb];
    float o[4];
    o[0] = acc[0] * inv + t.x;
    o[1] = acc[1] * inv + t.y;
    o[2] = acc[2] * inv + t.z;
    o[3] = acc[3] * inv + t.w;

    float s = o[0] + o[1] + o[2] + o[3];
#pragma unroll
    for (int d = 1; d < 64; d <<= 1) s += __shfl_xor(s, d);
    float mu = s * (1.f / 256.f);
    float vs = 0.f;
#pragma unroll
    for (int j = 0; j < 4; j++) { float dd = o[j] - mu; vs += dd * dd; }
#pragma unroll
    for (int d = 1; d < 64; d <<= 1) vs += __shfl_xor(vs, d);
    float rstd = rsqrtf(vs * (1.f / 256.f) + LN_EPS);

    float4 w4 = *(const float4*)&lnw[cb];
    float4 b4 = *(const float4*)&lnb[cb];
    ushort4 outv;
    outv.x = f2bu(fmaxf((o[0] - mu) * rstd * w4.x + b4.x, 0.f));
    outv.y = f2bu(fmaxf((o[1] - mu) * rstd * w4.y + b4.y, 0.f));
    outv.z = f2bu(fmaxf((o[2] - mu) * rstd * w4.z + b4.z, 0.f));
    outv.w = f2bu(fmaxf((o[3] - mu) * rstd * w4.w + b4.w, 0.f));
    *(ushort4*)&hout[(size_t)node * H + cb] = outv;
}

// ---------------------------------------------------------------------------
// Pool BEFORE projection (linearity reorder). Stage 1: segmented atomic sums.
// 256 blocks over contiguous node chunks; thread c owns channel c; flush on
// graph boundary (~1.25 flushes/block).
// ---------------------------------------------------------------------------
__global__ __launch_bounds__(256) void k_pool_sum(
    const unsigned short* __restrict__ hb, const int* __restrict__ batch,
    float* __restrict__ pooled, int N) {
    int c = threadIdx.x;
    int chunk = (N + gridDim.x - 1) / gridDim.x;
    int n0 = blockIdx.x * chunk;
    int n1 = min(n0 + chunk, N);
    if (n0 >= n1) return;
    float acc = 0.f;
    int cur = batch[n0];
    for (int n = n0; n < n1; n++) {
        int g = batch[n];
        if (g != cur) {
            atomicAdd(&pooled[cur * H + c], acc);
            acc = 0.f; cur = g;
        }
        acc += b2f(hb[(size_t)n * H + c]);
    }
    atomicAdd(&pooled[cur * H + c], acc);
}

// Stage 2: out[g] = (pooled[g]/cnt) @ lin_W + lin_b  (64x256x256 micro-GEMM).
// Empty graph -> out = 0 (matches reference segment_sum semantics).
__global__ __launch_bounds__(256) void k_lin_pool(
    const float* __restrict__ pooled, const int* __restrict__ batch,
    const float* __restrict__ linW, const float* __restrict__ linb,
    float* __restrict__ out, int N) {
    __shared__ float row[H];
    __shared__ int s_lo, s_hi;
    int g = blockIdx.x, c = threadIdx.x;
    if (c == 0) {
        int lo = 0, hi = N;
        while (lo < hi) { int mid = (lo + hi) >> 1; if (batch[mid] < g) lo = mid + 1; else hi = mid; }
        s_lo = lo;
    }
    if (c == 1) {
        int lo = 0, hi = N;
        while (lo < hi) { int mid = (lo + hi) >> 1; if (batch[mid] < g + 1) lo = mid + 1; else hi = mid; }
        s_hi = lo;
    }
    __syncthreads();
    int cnt = s_hi - s_lo;
    float scale = (cnt > 0) ? 1.f / (float)cnt : 0.f;
    row[c] = pooled[g * H + c] * scale;
    __syncthreads();
    float acc = (cnt > 0) ? linb[c] : 0.f;
#pragma unroll 8
    for (int k = 0; k < H; k++) acc = fmaf(row[k], linW[k * H + c], acc);
    out[g * H + c] = acc;
}

// ---------------------------------------------------------------------------
extern "C" void kernel_launch(void* const* d_in, const int* in_sizes, int n_in,
                              void* d_out, int out_size, void* d_ws, size_t ws_size,
                              hipStream_t stream) {
    const float* x        = (const float*)d_in[0];
    const int*   ei       = (const int*)d_in[1];
    const float* eattr    = (const float*)d_in[2];
    const int*   batch    = (const int*)d_in[3];
    const float* W_l0     = (const float*)d_in[4];
    const float* W_r0     = (const float*)d_in[5];
    const float* W_l      = (const float*)d_in[6];
    const float* W_r      = (const float*)d_in[7];
    const float* b_l      = (const float*)d_in[8];
    const float* b_r      = (const float*)d_in[9];
    const float* W_e      = (const float*)d_in[10];
    const float* att      = (const float*)d_in[11];
    const float* bias     = (const float*)d_in[12];
    const float* ln_w     = (const float*)d_in[13];
    const float* ln_b     = (const float*)d_in[14];
    const float* lin_W    = (const float*)d_in[15];
    const float* lin_b    = (const float*)d_in[16];

    const int N = in_sizes[0] / 23;          // 20000
    const int E = in_sizes[1] / 2;           // 320000
    const int G = out_size / H;              // 64
    const int L = 4;

    // workspace layout
    char* p = (char*)d_ws;
    float* hlf = (float*)p;                       p += (size_t)N * H * 4;
    float* hr  = (float*)p;                       p += (size_t)N * H * 4;
    float4* erec = (float4*)p;                    p += (size_t)E * 32;
    unsigned short* hb = (unsigned short*)p;      p += (size_t)NPAD * H * 2;
    __hip_bfloat16* xb  = (__hip_bfloat16*)p;     p += (size_t)NPAD * 32 * 2;
    __hip_bfloat16* w0t = (__hip_bfloat16*)p;     p += (size_t)2 * 256 * 32 * 2;
    __hip_bfloat16* wbig = (__hip_bfloat16*)p;    p += (size_t)6 * 65536 * 2;
    float* loop_attr = (float*)p;                 p += (size_t)N * 8 * 4;
    float* pooled = (float*)p;                    p += (size_t)G * H * 4;
    int* deg      = (int*)p;                      p += (size_t)N * 4;
    int* row_ptr  = (int*)p;                      p += (size_t)(N + 1) * 4;
    int* cursor   = (int*)p;                      p += (size_t)N * 4;

    __hip_bfloat16* Wl0t = w0t;
    __hip_bfloat16* Wr0t = w0t + 8192;
    __hip_bfloat16* Wlt  = wbig;
    __hip_bfloat16* Wrt  = wbig + (size_t)3 * 65536;

    hipMemsetAsync(deg, 0, (size_t)N * sizeof(int), stream);
    hipMemsetAsync(pooled, 0, (size_t)G * H * sizeof(float), stream);
    hipMemsetAsync(hb + (size_t)N * H, 0, (size_t)(NPAD - N) * H * 2, stream);

    int tb = 256;
    k_conv_x<<<(NPAD * 32 + tb - 1) / tb, tb, 0, stream>>>(x, xb, N);
    k_conv_w0<<<(2 * 256 * 32 + tb - 1) / tb, tb, 0, stream>>>(W_l0, W_r0, w0t);
    k_conv_w<<<(6 * 65536 + tb - 1) / tb, tb, 0, stream>>>(W_l, W_r, wbig);

    k_edge_hist<<<(E + tb - 1) / tb, tb, 0, stream>>>(ei, deg, E);
    k_scan<<<1, 1024, 0, stream>>>(deg, row_ptr, cursor, N, E);
    k_scatter<<<(E + tb - 1) / tb, tb, 0, stream>>>(ei, eattr, cursor, erec, E);
    k_loop_mean<<<(N + 3) / 4, 256, 0, stream>>>(row_ptr, erec, loop_attr, N);

    dim3 gdual(4, NPAD / 128), blk(256);

    for (int l = 0; l < L; l++) {
        const __hip_bfloat16* A  = (l == 0) ? xb : (const __hip_bfloat16*)hb;
        const __hip_bfloat16* Wl = (l == 0) ? Wl0t : (Wlt + (size_t)(l - 1) * 65536);
        const __hip_bfloat16* Wr = (l == 0) ? Wr0t : (Wrt + (size_t)(l - 1) * 65536);
        if (l == 0)
            k_gemm_mfma<32><<<gdual, blk, 0, stream>>>(A, N, Wl, b_l + l * H, hlf,
                                                       Wr, b_r + l * H, hr);
        else
            k_gemm_mfma<256><<<gdual, blk, 0, stream>>>(A, N, Wl, b_l + l * H, hlf,
                                                        Wr, b_r + l * H, hr);
        k_gat<<<(N + 3) / 4, 256, 0, stream>>>(hlf, hr, row_ptr, erec, loop_attr,
                                               W_e + (size_t)l * EDIM * H, att + l * H,
                                               bias + l * H, ln_w + l * H, ln_b + l * H, hb, N);
    }

    // pool-then-project (linearity reorder): mean(h) @ lin_W + lin_b
    k_pool_sum<<<256, 256, 0, stream>>>(hb, batch, pooled, N);
    k_lin_pool<<<G, 256, 0, stream>>>(pooled, batch, lin_W, lin_b, (float*)d_out, N);
}

// Round 7
// 529.671 us; speedup vs baseline: 1.4481x; 1.1263x over previous
//
#include <hip/hip_runtime.h>
#include <hip/hip_bf16.h>
#include <math.h>

#define H 256
#define EDIM 6
#define NEG 0.2f
#define LN_EPS 1e-5f
#define NPAD 20096   // 157 * 128

typedef __bf16 bf16x8 __attribute__((ext_vector_type(8)));
typedef float  floatx4 __attribute__((ext_vector_type(4)));
typedef float  f32x2   __attribute__((ext_vector_type(2)));

__device__ __forceinline__ float b2f(unsigned short u) {
    union { unsigned int i; float f; } v; v.i = ((unsigned int)u) << 16; return v.f;
}
__device__ __forceinline__ unsigned short f2bu(float f) {
    __hip_bfloat16 h = __float2bfloat16(f);
    return *(unsigned short*)&h;
}

// ---------------------------------------------------------------------------
// CSR build
// ---------------------------------------------------------------------------
__global__ void k_edge_hist(const int* __restrict__ ei, int* __restrict__ deg, int E) {
    int e = blockIdx.x * blockDim.x + threadIdx.x;
    if (e >= E) return;
    atomicAdd(&deg[ei[E + e]], 1);
}

// --- hierarchical exclusive scan (replaces single-block k_scan) ---
__global__ __launch_bounds__(256) void k_scan1(const int* __restrict__ deg,
                                               int* __restrict__ row_ptr,
                                               int* __restrict__ bsum, int N) {
    __shared__ int ws[4];
    int tid = threadIdx.x, gid = blockIdx.x * 256 + tid;
    int lane = tid & 63, w = tid >> 6;
    int v = (gid < N) ? deg[gid] : 0;
    int x = v;
#pragma unroll
    for (int d = 1; d < 64; d <<= 1) { int y = __shfl_up(x, d); if (lane >= d) x += y; }
    if (lane == 63) ws[w] = x;
    __syncthreads();
    int off = 0;
#pragma unroll
    for (int i = 0; i < 4; i++) off += (i < w) ? ws[i] : 0;
    if (gid < N) row_ptr[gid] = off + x - v;     // local exclusive prefix
    if (tid == 255) bsum[blockIdx.x] = off + x;  // block total
}

__global__ __launch_bounds__(256) void k_scan2(int* __restrict__ bsum, int nb) {
    __shared__ int ws[4];
    int tid = threadIdx.x;
    int lane = tid & 63, w = tid >> 6;
    int v = (tid < nb) ? bsum[tid] : 0;
    int x = v;
#pragma unroll
    for (int d = 1; d < 64; d <<= 1) { int y = __shfl_up(x, d); if (lane >= d) x += y; }
    if (lane == 63) ws[w] = x;
    __syncthreads();
    int off = 0;
#pragma unroll
    for (int i = 0; i < 4; i++) off += (i < w) ? ws[i] : 0;
    if (tid < nb) bsum[tid] = off + x - v;       // exclusive block offsets
}

__global__ __launch_bounds__(256) void k_scan3(int* __restrict__ row_ptr,
                                               int* __restrict__ cursor,
                                               const int* __restrict__ bsum, int N, int E) {
    int gid = blockIdx.x * 256 + threadIdx.x;
    if (gid < N) {
        int v = row_ptr[gid] + bsum[blockIdx.x];
        row_ptr[gid] = v;
        cursor[gid] = v;
    }
    if (gid == 0) row_ptr[N] = E;
}

// 32B edge record: {src_byte_off (as float bits), ea0..ea5, pad}
__global__ void k_scatter(const int* __restrict__ ei, const float* __restrict__ eattr,
                          int* __restrict__ cursor, float4* __restrict__ erec, int E) {
    int e = blockIdx.x * blockDim.x + threadIdx.x;
    if (e >= E) return;
    int s = ei[e], d = ei[E + e];
    int pos = atomicAdd(&cursor[d], 1);
    float4 ra, rb;
    ra.x = __int_as_float(s << 10);   // byte offset into fp32 [N,256] row
    ra.y = eattr[e * EDIM + 0];
    ra.z = eattr[e * EDIM + 1];
    ra.w = eattr[e * EDIM + 2];
    rb.x = eattr[e * EDIM + 3];
    rb.y = eattr[e * EDIM + 4];
    rb.z = eattr[e * EDIM + 5];
    rb.w = 0.f;
    erec[(size_t)pos * 2]     = ra;
    erec[(size_t)pos * 2 + 1] = rb;
}

// loop_attr[node][0..5] = mean of incoming edge attrs (layer-invariant)
__global__ __launch_bounds__(256) void k_loop_mean(const int* __restrict__ row_ptr,
                                                   const float4* __restrict__ erec,
                                                   float* __restrict__ loop_attr, int N) {
    int wv = threadIdx.x >> 6, lane = threadIdx.x & 63;
    int node = blockIdx.x * 4 + wv;
    if (node >= N) return;
    int e0 = row_ptr[node], e1 = row_ptr[node + 1];
    float es[6] = {0.f, 0.f, 0.f, 0.f, 0.f, 0.f};
    for (int e = e0 + lane; e < e1; e += 64) {
        float4 ra = erec[(size_t)e * 2];
        float4 rb = erec[(size_t)e * 2 + 1];
        es[0] += ra.y; es[1] += ra.z; es[2] += ra.w;
        es[3] += rb.x; es[4] += rb.y; es[5] += rb.z;
    }
#pragma unroll
    for (int d = 1; d < 64; d <<= 1) {
#pragma unroll
        for (int k = 0; k < 6; k++) es[k] += __shfl_xor(es[k], d);
    }
    if (lane == 0) {
        float inv = 1.f / fmaxf((float)(e1 - e0), 1.f);
        float4 a, b;
        a.x = es[0] * inv; a.y = es[1] * inv; a.z = es[2] * inv; a.w = es[3] * inv;
        b.x = es[4] * inv; b.y = es[5] * inv; b.z = 0.f; b.w = 0.f;
        *(float4*)&loop_attr[(size_t)node * 8]     = a;
        *(float4*)&loop_attr[(size_t)node * 8 + 4] = b;
    }
}

// ---------------------------------------------------------------------------
// Weight conversions to transposed bf16 [c][k]
// ---------------------------------------------------------------------------
__global__ void k_conv_x(const float* __restrict__ x, __hip_bfloat16* __restrict__ xb, int N) {
    int idx = blockIdx.x * blockDim.x + threadIdx.x;
    if (idx >= NPAD * 32) return;
    int r = idx >> 5, k = idx & 31;
    float v = (r < N && k < 23) ? x[r * 23 + k] : 0.f;
    xb[idx] = __float2bfloat16(v);
}

__global__ void k_conv_w0(const float* __restrict__ Wl0, const float* __restrict__ Wr0,
                          __hip_bfloat16* __restrict__ out) {
    int idx = blockIdx.x * blockDim.x + threadIdx.x;
    if (idx >= 2 * 256 * 32) return;
    int mat = idx >> 13, rem = idx & 8191;
    int c = rem >> 5, k = rem & 31;
    const float* W = mat ? Wr0 : Wl0;
    float v = (k < 23) ? W[k * 256 + c] : 0.f;
    out[idx] = __float2bfloat16(v);
}

__global__ void k_conv_w(const float* __restrict__ Wl, const float* __restrict__ Wr,
                         __hip_bfloat16* __restrict__ out) {
    int idx = blockIdx.x * blockDim.x + threadIdx.x;
    if (idx >= 6 * 65536) return;
    int mat = idx >> 16, rem = idx & 65535;
    int c = rem >> 8, k = rem & 255;
    const float* W = (mat < 3) ? (Wl + (size_t)mat * 65536)
                   : (Wr + (size_t)(mat - 3) * 65536);
    out[idx] = __float2bfloat16(W[k * 256 + c]);
}

// ---------------------------------------------------------------------------
// MFMA dual GEMM, K compile-time. f32 outputs. (unchanged)
// ---------------------------------------------------------------------------
template<int K>
__global__ __launch_bounds__(256) void k_gemm_mfma(
    const __hip_bfloat16* __restrict__ A, int N,
    const __hip_bfloat16* __restrict__ Wt1, const float* __restrict__ b1,
    float* __restrict__ C1,
    const __hip_bfloat16* __restrict__ Wt2, const float* __restrict__ b2,
    float* __restrict__ C2) {
    int tid = threadIdx.x;
    int wv = tid >> 6, lane = tid & 63;
    int quad = lane >> 4, l16 = lane & 15;
    int mat = blockIdx.x >> 1;
    int c0 = (blockIdx.x & 1) * 128;
    int r0 = blockIdx.y * 128;
    const __hip_bfloat16* Wt = mat ? Wt2 : Wt1;
    const float* bv = mat ? b2 : b1;
    float* C = mat ? C2 : C1;
    int wm = wv >> 1, wn = wv & 1;
    int rbase = r0 + wm * 64;
    int cbase = c0 + wn * 64;

    floatx4 acc[4][4] = {};
    const __bf16* Ab = (const __bf16*)A;
    const __bf16* Bb = (const __bf16*)Wt;
#pragma unroll 2
    for (int k0 = 0; k0 < K; k0 += 32) {
        bf16x8 a[4], b[4];
        const __bf16* Ap = Ab + (size_t)(rbase + l16) * K + k0 + quad * 8;
#pragma unroll
        for (int mi = 0; mi < 4; mi++)
            a[mi] = *(const bf16x8*)(Ap + (size_t)mi * 16 * K);
        const __bf16* Bp = Bb + (size_t)(cbase + l16) * K + k0 + quad * 8;
#pragma unroll
        for (int ni = 0; ni < 4; ni++)
            b[ni] = *(const bf16x8*)(Bp + (size_t)ni * 16 * K);
#pragma unroll
        for (int mi = 0; mi < 4; mi++)
#pragma unroll
            for (int ni = 0; ni < 4; ni++)
                acc[mi][ni] = __builtin_amdgcn_mfma_f32_16x16x32_bf16(a[mi], b[ni], acc[mi][ni], 0, 0, 0);
    }
#pragma unroll
    for (int ni = 0; ni < 4; ni++) {
        int c = cbase + ni * 16 + l16;
        float bb = bv[c];
#pragma unroll
        for (int mi = 0; mi < 4; mi++) {
#pragma unroll
            for (int r = 0; r < 4; r++) {
                int gr = rbase + mi * 16 + quad * 4 + r;
                if (gr < N) C[(size_t)gr * H + c] = acc[mi][ni][r] + bb;
            }
        }
    }
}

// ---------------------------------------------------------------------------
// Fused GATv2 edge pass v5: packed-fp32 (f32x2 -> v_pk_fma_f32) channel math,
// one wave per node, 32B fp32 edge records, fp32 gathers, flat softmax,
// select-free main loop + predicated tail, fused LN+ReLU, bf16 out.
// ---------------------------------------------------------------------------
__global__ __launch_bounds__(256) void k_gat(
    const float* __restrict__ hlf, const float* __restrict__ hr,
    const int* __restrict__ row_ptr, const float4* __restrict__ erec,
    const float* __restrict__ loop_attr,
    const float* __restrict__ We, const float* __restrict__ attv,
    const float* __restrict__ bias, const float* __restrict__ lnw,
    const float* __restrict__ lnb, unsigned short* __restrict__ hout, int N) {
    int wv = threadIdx.x >> 6;
    int lane = threadIdx.x & 63;
    int node = blockIdx.x * 4 + wv;
    if (node >= N) return;
    int cb = lane * 4;
    int cb4 = cb * 4;
    const char* hbase = (const char*)hlf;

    f32x2 we2[EDIM][2];
#pragma unroll
    for (int k = 0; k < EDIM; k++) {
        float4 t = *(const float4*)&We[k * H + cb];
        we2[k][0] = (f32x2){t.x, t.y};
        we2[k][1] = (f32x2){t.z, t.w};
    }
    float4 t;
    t = *(const float4*)&attv[cb];
    f32x2 av0 = {t.x, t.y}, av1 = {t.z, t.w};
    t = *(const float4*)&hr[(size_t)node * H + cb];
    f32x2 hr0 = {t.x, t.y}, hr1 = {t.z, t.w};
    t = *(const float4*)&hlf[(size_t)node * H + cb];
    f32x2 hl0 = {t.x, t.y}, hl1 = {t.z, t.w};

    float denom = 0.f;
    f32x2 acc0 = {0.f, 0.f}, acc1 = {0.f, 0.f};

    int e0 = row_ptr[node], e1 = row_ptr[node + 1];
    int deg = e1 - e0;
    int gfull = deg >> 2;

    for (int g = 0; g < gfull; g++) {
        int base = e0 + g * 4;
        f32x2 hsa[4], hsb[4];
        float p[4];
#pragma unroll
        for (int i = 0; i < 4; i++) {
            float4 ra = erec[(size_t)(base + i) * 2];
            float4 rb = erec[(size_t)(base + i) * 2 + 1];
            float4 h4 = *(const float4*)(hbase + (__float_as_int(ra.x) + cb4));
            hsa[i] = (f32x2){h4.x, h4.y};
            hsb[i] = (f32x2){h4.z, h4.w};
            f32x2 t0 = hr0, t1 = hr1;
            t0 += ra.y * we2[0][0]; t1 += ra.y * we2[0][1];
            t0 += ra.z * we2[1][0]; t1 += ra.z * we2[1][1];
            t0 += ra.w * we2[2][0]; t1 += ra.w * we2[2][1];
            t0 += rb.x * we2[3][0]; t1 += rb.x * we2[3][1];
            t0 += rb.y * we2[4][0]; t1 += rb.y * we2[4][1];
            t0 += rb.z * we2[5][0]; t1 += rb.z * we2[5][1];
            f32x2 v0 = hsa[i] + t0;
            f32x2 v1 = hsb[i] + t1;
            v0 = __builtin_elementwise_max(v0, v0 * NEG);   // leaky_relu
            v1 = __builtin_elementwise_max(v1, v1 * NEG);
            f32x2 pd = v0 * av0;
            pd += v1 * av1;
            p[i] = pd.x + pd.y;
        }
#pragma unroll
        for (int d = 1; d < 64; d <<= 1) {
#pragma unroll
            for (int i = 0; i < 4; i++) p[i] += __shfl_xor(p[i], d);
        }
        float w0 = __expf(p[0]), w1 = __expf(p[1]);
        float w2 = __expf(p[2]), w3 = __expf(p[3]);
        denom += (w0 + w1) + (w2 + w3);
        acc0 += w0 * hsa[0]; acc1 += w0 * hsb[0];
        acc0 += w1 * hsa[1]; acc1 += w1 * hsb[1];
        acc0 += w2 * hsa[2]; acc1 += w2 * hsb[2];
        acc0 += w3 * hsa[3]; acc1 += w3 * hsb[3];
    }

    int trem = deg & 3;
    if (trem) {
        int base = e0 + gfull * 4;
        f32x2 hsa[4], hsb[4];
        float p[4];
#pragma unroll
        for (int i = 0; i < 4; i++) {
            int idx = (i < trem) ? (base + i) : base;
            float4 ra = erec[(size_t)idx * 2];
            float4 rb = erec[(size_t)idx * 2 + 1];
            float4 h4 = *(const float4*)(hbase + (__float_as_int(ra.x) + cb4));
            hsa[i] = (f32x2){h4.x, h4.y};
            hsb[i] = (f32x2){h4.z, h4.w};
            f32x2 t0 = hr0, t1 = hr1;
            t0 += ra.y * we2[0][0]; t1 += ra.y * we2[0][1];
            t0 += ra.z * we2[1][0]; t1 += ra.z * we2[1][1];
            t0 += ra.w * we2[2][0]; t1 += ra.w * we2[2][1];
            t0 += rb.x * we2[3][0]; t1 += rb.x * we2[3][1];
            t0 += rb.y * we2[4][0]; t1 += rb.y * we2[4][1];
            t0 += rb.z * we2[5][0]; t1 += rb.z * we2[5][1];
            f32x2 v0 = hsa[i] + t0;
            f32x2 v1 = hsb[i] + t1;
            v0 = __builtin_elementwise_max(v0, v0 * NEG);
            v1 = __builtin_elementwise_max(v1, v1 * NEG);
            f32x2 pd = v0 * av0;
            pd += v1 * av1;
            p[i] = pd.x + pd.y;
        }
#pragma unroll
        for (int d = 1; d < 64; d <<= 1) {
#pragma unroll
            for (int i = 0; i < 4; i++) p[i] += __shfl_xor(p[i], d);
        }
        float w[4];
#pragma unroll
        for (int i = 0; i < 4; i++)
            w[i] = (i < trem) ? __expf(p[i]) : 0.f;
        denom += (w[0] + w[1]) + (w[2] + w[3]);
#pragma unroll
        for (int i = 0; i < 4; i++) { acc0 += w[i] * hsa[i]; acc1 += w[i] * hsb[i]; }
    }

    // self loop with precomputed mean attrs
    {
        float4 la0 = *(const float4*)&loop_attr[(size_t)node * 8];
        float4 la1 = *(const float4*)&loop_attr[(size_t)node * 8 + 4];
        f32x2 t0 = hl0 + hr0, t1 = hl1 + hr1;
        t0 += la0.x * we2[0][0]; t1 += la0.x * we2[0][1];
        t0 += la0.y * we2[1][0]; t1 += la0.y * we2[1][1];
        t0 += la0.z * we2[2][0]; t1 += la0.z * we2[2][1];
        t0 += la0.w * we2[3][0]; t1 += la0.w * we2[3][1];
        t0 += la1.x * we2[4][0]; t1 += la1.x * we2[4][1];
        t0 += la1.y * we2[5][0]; t1 += la1.y * we2[5][1];
        t0 = __builtin_elementwise_max(t0, t0 * NEG);
        t1 = __builtin_elementwise_max(t1, t1 * NEG);
        f32x2 pd = t0 * av0;
        pd += t1 * av1;
        float p = pd.x + pd.y;
#pragma unroll
        for (int d = 1; d < 64; d <<= 1) p += __shfl_xor(p, d);
        float w = __expf(p);
        denom += w;
        acc0 += w * hl0; acc1 += w * hl1;
    }

    float inv = 1.f / denom;
    t = *(const float4*)&bias[cb];
    float o[4];
    o[0] = acc0.x * inv + t.x;
    o[1] = acc0.y * inv + t.y;
    o[2] = acc1.x * inv + t.z;
    o[3] = acc1.y * inv + t.w;

    float s = o[0] + o[1] + o[2] + o[3];
#pragma unroll
    for (int d = 1; d < 64; d <<= 1) s += __shfl_xor(s, d);
    float mu = s * (1.f / 256.f);
    float vs = 0.f;
#pragma unroll
    for (int j = 0; j < 4; j++) { float dd = o[j] - mu; vs += dd * dd; }
#pragma unroll
    for (int d = 1; d < 64; d <<= 1) vs += __shfl_xor(vs, d);
    float rstd = rsqrtf(vs * (1.f / 256.f) + LN_EPS);

    float4 w4 = *(const float4*)&lnw[cb];
    float4 b4 = *(const float4*)&lnb[cb];
    ushort4 outv;
    outv.x = f2bu(fmaxf((o[0] - mu) * rstd * w4.x + b4.x, 0.f));
    outv.y = f2bu(fmaxf((o[1] - mu) * rstd * w4.y + b4.y, 0.f));
    outv.z = f2bu(fmaxf((o[2] - mu) * rstd * w4.z + b4.z, 0.f));
    outv.w = f2bu(fmaxf((o[3] - mu) * rstd * w4.w + b4.w, 0.f));
    *(ushort4*)&hout[(size_t)node * H + cb] = outv;
}

// ---------------------------------------------------------------------------
// Pool BEFORE projection (linearity reorder). Stage 1: segmented atomic sums.
// ---------------------------------------------------------------------------
__global__ __launch_bounds__(256) void k_pool_sum(
    const unsigned short* __restrict__ hb, const int* __restrict__ batch,
    float* __restrict__ pooled, int N) {
    int c = threadIdx.x;
    int chunk = (N + gridDim.x - 1) / gridDim.x;
    int n0 = blockIdx.x * chunk;
    int n1 = min(n0 + chunk, N);
    if (n0 >= n1) return;
    float acc = 0.f;
    int cur = batch[n0];
    for (int n = n0; n < n1; n++) {
        int g = batch[n];
        if (g != cur) {
            atomicAdd(&pooled[cur * H + c], acc);
            acc = 0.f; cur = g;
        }
        acc += b2f(hb[(size_t)n * H + c]);
    }
    atomicAdd(&pooled[cur * H + c], acc);
}

// Stage 2: out[g] = (pooled[g]/cnt) @ lin_W + lin_b  (64x256x256 micro-GEMM).
__global__ __launch_bounds__(256) void k_lin_pool(
    const float* __restrict__ pooled, const int* __restrict__ batch,
    const float* __restrict__ linW, const float* __restrict__ linb,
    float* __restrict__ out, int N) {
    __shared__ float row[H];
    __shared__ int s_lo, s_hi;
    int g = blockIdx.x, c = threadIdx.x;
    if (c == 0) {
        int lo = 0, hi = N;
        while (lo < hi) { int mid = (lo + hi) >> 1; if (batch[mid] < g) lo = mid + 1; else hi = mid; }
        s_lo = lo;
    }
    if (c == 1) {
        int lo = 0, hi = N;
        while (lo < hi) { int mid = (lo + hi) >> 1; if (batch[mid] < g + 1) lo = mid + 1; else hi = mid; }
        s_hi = lo;
    }
    __syncthreads();
    int cnt = s_hi - s_lo;
    float scale = (cnt > 0) ? 1.f / (float)cnt : 0.f;
    row[c] = pooled[g * H + c] * scale;
    __syncthreads();
    float acc = (cnt > 0) ? linb[c] : 0.f;
#pragma unroll 8
    for (int k = 0; k < H; k++) acc = fmaf(row[k], linW[k * H + c], acc);
    out[g * H + c] = acc;
}

// ---------------------------------------------------------------------------
extern "C" void kernel_launch(void* const* d_in, const int* in_sizes, int n_in,
                              void* d_out, int out_size, void* d_ws, size_t ws_size,
                              hipStream_t stream) {
    const float* x        = (const float*)d_in[0];
    const int*   ei       = (const int*)d_in[1];
    const float* eattr    = (const float*)d_in[2];
    const int*   batch    = (const int*)d_in[3];
    const float* W_l0     = (const float*)d_in[4];
    const float* W_r0     = (const float*)d_in[5];
    const float* W_l      = (const float*)d_in[6];
    const float* W_r      = (const float*)d_in[7];
    const float* b_l      = (const float*)d_in[8];
    const float* b_r      = (const float*)d_in[9];
    const float* W_e      = (const float*)d_in[10];
    const float* att      = (const float*)d_in[11];
    const float* bias     = (const float*)d_in[12];
    const float* ln_w     = (const float*)d_in[13];
    const float* ln_b     = (const float*)d_in[14];
    const float* lin_W    = (const float*)d_in[15];
    const float* lin_b    = (const float*)d_in[16];

    const int N = in_sizes[0] / 23;          // 20000
    const int E = in_sizes[1] / 2;           // 320000
    const int G = out_size / H;              // 64
    const int L = 4;

    // workspace layout
    char* p = (char*)d_ws;
    float* hlf = (float*)p;                       p += (size_t)N * H * 4;
    float* hr  = (float*)p;                       p += (size_t)N * H * 4;
    float4* erec = (float4*)p;                    p += (size_t)E * 32;
    unsigned short* hb = (unsigned short*)p;      p += (size_t)NPAD * H * 2;
    __hip_bfloat16* xb  = (__hip_bfloat16*)p;     p += (size_t)NPAD * 32 * 2;
    __hip_bfloat16* w0t = (__hip_bfloat16*)p;     p += (size_t)2 * 256 * 32 * 2;
    __hip_bfloat16* wbig = (__hip_bfloat16*)p;    p += (size_t)6 * 65536 * 2;
    float* loop_attr = (float*)p;                 p += (size_t)N * 8 * 4;
    float* pooled = (float*)p;                    p += (size_t)G * H * 4;
    int* deg      = (int*)p;                      p += (size_t)N * 4;
    int* row_ptr  = (int*)p;                      p += (size_t)(N + 1) * 4;
    int* cursor   = (int*)p;                      p += (size_t)N * 4;
    int* bsum     = (int*)p;                      p += (size_t)256 * 4;

    __hip_bfloat16* Wl0t = w0t;
    __hip_bfloat16* Wr0t = w0t + 8192;
    __hip_bfloat16* Wlt  = wbig;
    __hip_bfloat16* Wrt  = wbig + (size_t)3 * 65536;

    hipMemsetAsync(deg, 0, (size_t)N * sizeof(int), stream);
    hipMemsetAsync(pooled, 0, (size_t)G * H * sizeof(float), stream);
    hipMemsetAsync(hb + (size_t)N * H, 0, (size_t)(NPAD - N) * H * 2, stream);

    int tb = 256;
    k_conv_x<<<(NPAD * 32 + tb - 1) / tb, tb, 0, stream>>>(x, xb, N);
    k_conv_w0<<<(2 * 256 * 32 + tb - 1) / tb, tb, 0, stream>>>(W_l0, W_r0, w0t);
    k_conv_w<<<(6 * 65536 + tb - 1) / tb, tb, 0, stream>>>(W_l, W_r, wbig);

    k_edge_hist<<<(E + tb - 1) / tb, tb, 0, stream>>>(ei, deg, E);
    int nb = (N + 255) / 256;
    k_scan1<<<nb, 256, 0, stream>>>(deg, row_ptr, bsum, N);
    k_scan2<<<1, 256, 0, stream>>>(bsum, nb);
    k_scan3<<<nb, 256, 0, stream>>>(row_ptr, cursor, bsum, N, E);
    k_scatter<<<(E + tb - 1) / tb, tb, 0, stream>>>(ei, eattr, cursor, erec, E);
    k_loop_mean<<<(N + 3) / 4, 256, 0, stream>>>(row_ptr, erec, loop_attr, N);

    dim3 gdual(4, NPAD / 128), blk(256);

    for (int l = 0; l < L; l++) {
        const __hip_bfloat16* A  = (l == 0) ? xb : (const __hip_bfloat16*)hb;
        const __hip_bfloat16* Wl = (l == 0) ? Wl0t : (Wlt + (size_t)(l - 1) * 65536);
        const __hip_bfloat16* Wr = (l == 0) ? Wr0t : (Wrt + (size_t)(l - 1) * 65536);
        if (l == 0)
            k_gemm_mfma<32><<<gdual, blk, 0, stream>>>(A, N, Wl, b_l + l * H, hlf,
                                                       Wr, b_r + l * H, hr);
        else
            k_gemm_mfma<256><<<gdual, blk, 0, stream>>>(A, N, Wl, b_l + l * H, hlf,
                                                        Wr, b_r + l * H, hr);
        k_gat<<<(N + 3) / 4, 256, 0, stream>>>(hlf, hr, row_ptr, erec, loop_attr,
                                               W_e + (size_t)l * EDIM * H, att + l * H,
                                               bias + l * H, ln_w + l * H, ln_b + l * H, hb, N);
    }

    // pool-then-project (linearity reorder): mean(h) @ lin_W + lin_b
    k_pool_sum<<<256, 256, 0, stream>>>(hb, batch, pooled, N);
    k_lin_pool<<<G, 256, 0, stream>>>(pooled, batch, lin_W, lin_b, (float*)d_out, N);
}